// Round 1
// baseline (472.235 us; speedup 1.0000x reference)
//
#include <hip/hip_runtime.h>
#include <stdint.h>

typedef __attribute__((ext_vector_type(8))) short bf16x8;
typedef __attribute__((ext_vector_type(4))) float f32x4;

__device__ __forceinline__ unsigned short f2bf(float f) {
    union { float f; uint32_t u; } v; v.f = f;
    uint32_t r = (v.u + 0x7FFFu + ((v.u >> 16) & 1u)) >> 16;
    return (unsigned short)r;
}
__device__ __forceinline__ float bf2f(unsigned short u) {
    union { uint32_t u; float f; } v; v.u = ((uint32_t)u) << 16; return v.f;
}

#define WP_ELEMS  1081344      // 64 ktiles * 528 rows * 32 k
#define K2        15456        // head-GEMM K: 30*512 sampled + 96 coord slots (90 used)
#define W2P_ELEMS (144 * K2)   // 2,225,664
#define B_OFF     42240        // LDS byte offset of B staging (A is 528*80=42240)

// ---- pack conv weights (+shape/cam rows 512..524) to bf16, K-tiled [kt][row][k] ----
__global__ void pack_convw_kernel(const float* __restrict__ cw,
                                  const float* __restrict__ sw,
                                  const float* __restrict__ camw,
                                  unsigned short* __restrict__ Wp) {
    int gid = blockIdx.x * 256 + threadIdx.x;
    if (gid >= WP_ELEMS) return;
    int kt  = gid / 16896;
    int rem = gid - kt * 16896;
    int row = rem >> 5;
    int c   = rem & 31;
    int k   = kt * 32 + c;
    float v = 0.f;
    if (row < 512)      v = cw[row * 2048 + k];
    else if (row < 522) v = sw[(row - 512) * 2048 + k];
    else if (row < 525) v = camw[(row - 522) * 2048 + k];
    Wp[gid] = f2bf(v);
}

// ---- pack root/pose weights to bf16 [o2][K2]; cols 15360.. are the coord columns ----
__global__ void pack_w2_kernel(const float* __restrict__ root_w,
                               const float* __restrict__ pose_w,
                               unsigned short* __restrict__ W2p) {
    int gid = blockIdx.x * 256 + threadIdx.x;
    if (gid >= W2P_ELEMS) return;
    int o2 = gid / K2;
    int kk = gid - o2 * K2;
    float v = 0.f;
    if (o2 < 132) {
        const float* wr = (o2 < 6) ? (root_w + o2 * 15450) : (pose_w + (o2 - 6) * 15450);
        if (kk < 15360) {
            int j = kk >> 9;
            int o = kk & 511;
            v = wr[j * 515 + o];
        } else {
            int c = kk - 15360;
            if (c < 90) {
                int j = c / 3, d = c - 3 * j;
                v = wr[j * 515 + 512 + d];
            }
        }
    }
    W2p[gid] = f2bf(v);
}

// ---- fold BN(eval)+conv bias into per-channel scale/bias ----
__global__ void bn_prep_kernel(const float* cb, const float* g, const float* be,
                               const float* m, const float* v, float* sbws) {
    int o = blockIdx.x * 256 + threadIdx.x;
    if (o >= 512) return;
    float s = g[o] * rsqrtf(v[o] + 1e-5f);
    sbws[2 * o]     = s;
    sbws[2 * o + 1] = be[o] + s * (cb[o] - m[o]);
}

// ---- main fused kernel: per-batch conv GEMM (+pooled rows) + BN/ReLU + bilinear sample ----
__global__ __launch_bounds__(256, 2)
void conv_main_kernel(const float* __restrict__ img,
                      const float* __restrict__ jc,
                      const unsigned short* __restrict__ Wp,
                      const float* __restrict__ sbws,
                      const float* __restrict__ shape_b,
                      const float* __restrict__ cam_b,
                      unsigned short* __restrict__ sampled,
                      float* __restrict__ out) {
    __shared__ __align__(16) char smem[65536 + 256];
    const int t    = threadIdx.x;
    const int lane = t & 63;
    const int w    = t >> 6;
    const int l15  = lane & 15;
    const int quad = lane >> 4;
    const int b    = blockIdx.x;

    f32x4 acc[8][4];
    f32x4 accX;
    #pragma unroll
    for (int mi = 0; mi < 8; ++mi)
        #pragma unroll
        for (int nt = 0; nt < 4; ++nt)
            acc[mi][nt] = (f32x4){0.f, 0.f, 0.f, 0.f};
    accX = (f32x4){0.f, 0.f, 0.f, 0.f};

    // B staging: lane owns hw position = lane, k-chunk = w*8..w*8+7 (one b128 write)
    const float* gBbase = img + (size_t)b * 131072 + (size_t)(w * 8) * 64 + lane;

    for (int kt = 0; kt < 64; ++kt) {
        __syncthreads();
        // A: 528x32 bf16 pre-packed tile, contiguous, 2112 16B chunks
        const int4* gA = (const int4*)(Wp + (size_t)kt * 16896);
        int4 ta[8];
        #pragma unroll
        for (int i = 0; i < 8; ++i) ta[i] = gA[t + 256 * i];
        int4 ta8;
        if (t < 64) ta8 = gA[t + 2048];
        // B: 32x64 f32 tile, coalesced dword loads
        const float* gB = gBbase + (size_t)(kt * 32) * 64;
        float fb[8];
        #pragma unroll
        for (int j = 0; j < 8; ++j) fb[j] = gB[j * 64];

        #pragma unroll
        for (int i = 0; i < 8; ++i) {
            int c2 = t + 256 * i;
            *(int4*)(smem + (c2 >> 2) * 80 + (c2 & 3) * 16) = ta[i];
        }
        if (t < 64) {
            int c2 = t + 2048;
            *(int4*)(smem + (c2 >> 2) * 80 + (c2 & 3) * 16) = ta8;
        }
        {
            int4 bv;
            bv.x = (int)((uint32_t)f2bf(fb[0]) | ((uint32_t)f2bf(fb[1]) << 16));
            bv.y = (int)((uint32_t)f2bf(fb[2]) | ((uint32_t)f2bf(fb[3]) << 16));
            bv.z = (int)((uint32_t)f2bf(fb[4]) | ((uint32_t)f2bf(fb[5]) << 16));
            bv.w = (int)((uint32_t)f2bf(fb[6]) | ((uint32_t)f2bf(fb[7]) << 16));
            *(int4*)(smem + B_OFF + lane * 80 + w * 16) = bv;
        }
        __syncthreads();

        bf16x8 bfr0 = *(const bf16x8*)(smem + B_OFF + (0  + l15) * 80 + quad * 16);
        bf16x8 bfr1 = *(const bf16x8*)(smem + B_OFF + (16 + l15) * 80 + quad * 16);
        bf16x8 bfr2 = *(const bf16x8*)(smem + B_OFF + (32 + l15) * 80 + quad * 16);
        bf16x8 bfr3 = *(const bf16x8*)(smem + B_OFF + (48 + l15) * 80 + quad * 16);
        #pragma unroll
        for (int mi = 0; mi < 8; ++mi) {
            bf16x8 afr = *(const bf16x8*)(smem + (w * 128 + mi * 16 + l15) * 80 + quad * 16);
            acc[mi][0] = __builtin_amdgcn_mfma_f32_16x16x32_bf16(afr, bfr0, acc[mi][0], 0, 0, 0);
            acc[mi][1] = __builtin_amdgcn_mfma_f32_16x16x32_bf16(afr, bfr1, acc[mi][1], 0, 0, 0);
            acc[mi][2] = __builtin_amdgcn_mfma_f32_16x16x32_bf16(afr, bfr2, acc[mi][2], 0, 0, 0);
            acc[mi][3] = __builtin_amdgcn_mfma_f32_16x16x32_bf16(afr, bfr3, acc[mi][3], 0, 0, 0);
        }
        {   // pooled rows 512..527 (shape_w/cam_w appended); wave w covers n-tile w
            bf16x8 afrX = *(const bf16x8*)(smem + (512 + l15) * 80 + quad * 16);
            bf16x8 bfrW = *(const bf16x8*)(smem + B_OFF + (w * 16 + l15) * 80 + quad * 16);
            accX = __builtin_amdgcn_mfma_f32_16x16x32_bf16(afrX, bfrW, accX, 0, 0, 0);
        }
    }

    __syncthreads();   // staging LDS dead; reuse as f (512 rows x 64 pos bf16, XOR swizzle)
    const float2* sb2 = (const float2*)sbws;
    #pragma unroll
    for (int mi = 0; mi < 8; ++mi) {
        #pragma unroll
        for (int r = 0; r < 4; ++r) {
            int row = w * 128 + mi * 16 + quad * 4 + r;
            float2 sb = sb2[row];
            #pragma unroll
            for (int nt = 0; nt < 4; ++nt) {
                int col = nt * 16 + l15;
                float v = fmaxf(acc[mi][nt][r] * sb.x + sb.y, 0.f);
                *(unsigned short*)(smem + row * 128 + (((col + row) & 63) << 1)) = f2bf(v);
            }
        }
    }
    // shape/cam: per-wave shuffle reduce (16 positions), cross-wave via LDS red area
    float* red = (float*)(smem + 65536);
    #pragma unroll
    for (int r = 0; r < 4; ++r) {
        float v = accX[r];
        v += __shfl_xor(v, 1);
        v += __shfl_xor(v, 2);
        v += __shfl_xor(v, 4);
        v += __shfl_xor(v, 8);
        if (l15 == 0) red[w * 16 + quad * 4 + r] = v;
    }
    __syncthreads();

    if (t < 16) {
        float v = (red[t] + red[16 + t] + red[32 + t] + red[48 + t]) * 0.015625f;
        if (t < 10)      out[67584 + b * 10 + t] = v + shape_b[t];
        else if (t < 13) out[72704 + b * 3 + (t - 10)] = v + cam_b[t - 10];
    }
    // append joint coords (bf16) as K-columns 15360..15455 of samp (pad 90..95 = 0)
    const float* jcb = jc + b * 90;
    if (t < 96) {
        float v = (t < 90) ? jcb[t] : 0.f;
        sampled[(size_t)b * K2 + 15360 + t] = f2bf(v);
    }

    // bilinear sampling: thread handles channels o=2t,2t+1; joint j == s for all threads
    unsigned int* outsamp = (unsigned int*)(sampled + (size_t)b * K2);
    const int o = 2 * t;
    for (int s = 0; s < 30; ++s) {
        float x = jcb[s * 3 + 0];
        float y = jcb[s * 3 + 1];
        float x0f = floorf(x), y0f = floorf(y);
        int x0 = (int)x0f, y0 = (int)y0f;
        int x1 = x0 + 1, y1 = y0 + 1;
        float wx1 = x - x0f, wy1 = y - y0f;
        float wx0 = 1.f - wx1, wy0 = 1.f - wy1;
        float vx0 = (x0 >= 0 && x0 < 8) ? 1.f : 0.f;
        float vx1 = (x1 >= 0 && x1 < 8) ? 1.f : 0.f;
        float vy0 = (y0 >= 0 && y0 < 8) ? 1.f : 0.f;
        float vy1 = (y1 >= 0 && y1 < 8) ? 1.f : 0.f;
        int cx0 = min(max(x0, 0), 7), cx1 = min(max(x1, 0), 7);
        int cy0 = min(max(y0, 0), 7), cy1 = min(max(y1, 0), 7);
        int p00 = cy0 * 8 + cx0, p01 = cy0 * 8 + cx1;
        int p10 = cy1 * 8 + cx0, p11 = cy1 * 8 + cx1;
        float w00 = wy0 * wx0 * vy0 * vx0, w01 = wy0 * wx1 * vy0 * vx1;
        float w10 = wy1 * wx0 * vy1 * vx0, w11 = wy1 * wx1 * vy1 * vx1;
        float vA = w00 * bf2f(*(unsigned short*)(smem + o * 128 + (((p00 + o) & 63) << 1)))
                 + w01 * bf2f(*(unsigned short*)(smem + o * 128 + (((p01 + o) & 63) << 1)))
                 + w10 * bf2f(*(unsigned short*)(smem + o * 128 + (((p10 + o) & 63) << 1)))
                 + w11 * bf2f(*(unsigned short*)(smem + o * 128 + (((p11 + o) & 63) << 1)));
        int o1 = o + 1;
        float vB = w00 * bf2f(*(unsigned short*)(smem + o1 * 128 + (((p00 + o1) & 63) << 1)))
                 + w01 * bf2f(*(unsigned short*)(smem + o1 * 128 + (((p01 + o1) & 63) << 1)))
                 + w10 * bf2f(*(unsigned short*)(smem + o1 * 128 + (((p10 + o1) & 63) << 1)))
                 + w11 * bf2f(*(unsigned short*)(smem + o1 * 128 + (((p11 + o1) & 63) << 1)));
        outsamp[s * 256 + t] = (uint32_t)f2bf(vA) | ((uint32_t)f2bf(vB) << 16);
    }
}

// ---- head GEMM: partials(31x8 blocks of 64x144) = feat(512xK2)bf16 @ W2p^T, K split by joint ----
__global__ __launch_bounds__(256, 4)
void gemm2_kernel(const unsigned short* __restrict__ sampled,
                  const unsigned short* __restrict__ W2p,
                  float* __restrict__ part) {
    __shared__ __align__(16) char smem[16640];   // A: 64*80=5120, B: 144*80=11520
    const int t    = threadIdx.x;
    const int lane = t & 63;
    const int w    = t >> 6;
    const int l15  = lane & 15;
    const int quad = lane >> 4;
    const int m0   = blockIdx.x * 64;
    const int j    = blockIdx.y;
    const int k0   = j * 512;              // j==30 -> 15360 (coord columns)
    const int ktn  = (j == 30) ? 3 : 16;

    f32x4 acc[9];
    #pragma unroll
    for (int nt = 0; nt < 9; ++nt) acc[nt] = (f32x4){0.f, 0.f, 0.f, 0.f};

    for (int kt = 0; kt < ktn; ++kt) {
        __syncthreads();
        {
            int r = t >> 2, ci = t & 3;
            int4 d = *(const int4*)(sampled + (size_t)(m0 + r) * K2 + k0 + kt * 32 + ci * 8);
            *(int4*)(smem + r * 80 + ci * 16) = d;
        }
        #pragma unroll
        for (int i = 0; i < 3; ++i) {
            int c2 = t + 256 * i;
            if (c2 < 576) {
                int r = c2 >> 2, ci = c2 & 3;
                int4 d = *(const int4*)(W2p + (size_t)r * K2 + k0 + kt * 32 + ci * 8);
                *(int4*)(smem + 5120 + r * 80 + ci * 16) = d;
            }
        }
        __syncthreads();
        bf16x8 a = *(const bf16x8*)(smem + (w * 16 + l15) * 80 + quad * 16);
        #pragma unroll
        for (int nt = 0; nt < 9; ++nt) {
            bf16x8 bfv = *(const bf16x8*)(smem + 5120 + (nt * 16 + l15) * 80 + quad * 16);
            acc[nt] = __builtin_amdgcn_mfma_f32_16x16x32_bf16(a, bfv, acc[nt], 0, 0, 0);
        }
    }
    float* pout = part + (size_t)(j * 8 + blockIdx.x) * 9216;   // 64*144
    #pragma unroll
    for (int nt = 0; nt < 9; ++nt) {
        #pragma unroll
        for (int r = 0; r < 4; ++r) {
            pout[(w * 16 + quad * 4 + r) * 144 + nt * 16 + l15] = acc[nt][r];
        }
    }
}

// ---- sum 31 K-partials + bias -> final root/pose outputs ----
__global__ void reduce_out_kernel(const float* __restrict__ part,
                                  const float* __restrict__ root_b,
                                  const float* __restrict__ pose_b,
                                  float* __restrict__ out) {
    int gid = blockIdx.x * 256 + threadIdx.x;    // exactly 67584
    int m  = gid / 132;
    int o2 = gid - m * 132;
    float s = (o2 < 6) ? root_b[o2] : pose_b[o2 - 6];
    const float* p = part + (size_t)(m >> 6) * 9216 + (m & 63) * 144 + o2;
    #pragma unroll
    for (int j = 0; j < 31; ++j) s += p[(size_t)j * 8 * 9216];
    if (o2 < 6) out[m * 6 + o2] = s;
    else        out[3072 + m * 126 + (o2 - 6)] = s;
}

extern "C" void kernel_launch(void* const* d_in, const int* in_sizes, int n_in,
                              void* d_out, int out_size, void* d_ws, size_t ws_size,
                              hipStream_t stream) {
    const float* img     = (const float*)d_in[0];
    const float* jc      = (const float*)d_in[1];
    const float* conv_w  = (const float*)d_in[2];
    const float* conv_b  = (const float*)d_in[3];
    const float* bn_g    = (const float*)d_in[4];
    const float* bn_be   = (const float*)d_in[5];
    const float* bn_m    = (const float*)d_in[6];
    const float* bn_v    = (const float*)d_in[7];
    const float* root_w  = (const float*)d_in[8];
    const float* root_b  = (const float*)d_in[9];
    const float* pose_w  = (const float*)d_in[10];
    const float* pose_b  = (const float*)d_in[11];
    const float* shape_w = (const float*)d_in[12];
    const float* shape_b = (const float*)d_in[13];
    const float* cam_w   = (const float*)d_in[14];
    const float* cam_b   = (const float*)d_in[15];
    float* out = (float*)d_out;
    char* ws = (char*)d_ws;

    unsigned short* Wp   = (unsigned short*)(ws);                    // 2,162,688 B
    unsigned short* W2p  = (unsigned short*)(ws + 2162688);          // 4,451,328 B
    unsigned short* samp = (unsigned short*)(ws + 6614016);          // 15,826,944 B
    float* part          = (float*)(ws + 22440960);                  // 9,142,272 B
    float* sbws          = (float*)(ws + 31583232);                  // 4,096 B

    pack_convw_kernel<<<4224, 256, 0, stream>>>(conv_w, shape_w, cam_w, Wp);
    pack_w2_kernel<<<8694, 256, 0, stream>>>(root_w, pose_w, W2p);
    bn_prep_kernel<<<2, 256, 0, stream>>>(conv_b, bn_g, bn_be, bn_m, bn_v, sbws);
    conv_main_kernel<<<512, 256, 0, stream>>>(img, jc, Wp, sbws, shape_b, cam_b,
                                              samp, out);
    gemm2_kernel<<<dim3(8, 31), 256, 0, stream>>>(samp, W2p, part);
    reduce_out_kernel<<<264, 256, 0, stream>>>(part, root_b, pose_b, out);
}

// Round 4
// 471.220 us; speedup vs baseline: 1.0022x; 1.0022x over previous
//
#include <hip/hip_runtime.h>
#include <stdint.h>

typedef __attribute__((ext_vector_type(8))) short bf16x8;
typedef __attribute__((ext_vector_type(4))) float f32x4;

__device__ __forceinline__ unsigned short f2bf(float f) {
    union { float f; uint32_t u; } v; v.f = f;
    uint32_t r = (v.u + 0x7FFFu + ((v.u >> 16) & 1u)) >> 16;
    return (unsigned short)r;
}
__device__ __forceinline__ float bf2f(unsigned short u) {
    union { uint32_t u; float f; } v; v.u = ((uint32_t)u) << 16; return v.f;
}

// async global->LDS, 16B per lane; LDS dest = wave-uniform base + lane*16
__device__ __forceinline__ void gload16(const void* g, void* l) {
    __builtin_amdgcn_global_load_lds(
        (const __attribute__((address_space(1))) unsigned int*)g,
        (__attribute__((address_space(3))) unsigned int*)l, 16, 0, 0);
}

#define WP_ELEMS  1081344      // 64 ktiles * 33 groups * 512 bf16
#define K2        15456        // head-GEMM K: 30*512 sampled + 96 coord slots (90 used)
#define W2P_ELEMS (144 * K2)   // 2,225,664

// conv_main LDS layout (bytes)
#define ABUF0  0
#define ABUF1  33792
#define BBUF0  67584
#define BBUF1  71680
#define REDOFF 75776
#define SMEM_SZ 76032

// ---- pack conv weights (+shape/cam rows 512..524) to bf16 ----
// Layout: [kt][group g=row>>4][kchunk q][row&15][e] -> chunk-major 1024B groups,
// exactly the LDS image for global_load_lds + conflict-free ds_read_b128.
__global__ void pack_convw_kernel(const float* __restrict__ cw,
                                  const float* __restrict__ sw,
                                  const float* __restrict__ camw,
                                  unsigned short* __restrict__ Wp) {
    int gid = blockIdx.x * 256 + threadIdx.x;
    if (gid >= WP_ELEMS) return;
    int kt  = gid / 16896;
    int rem = gid - kt * 16896;
    int g   = rem >> 9;          // 0..32
    int r2  = rem & 511;
    int q   = r2 >> 7;           // 0..3
    int rr  = (r2 >> 3) & 15;    // 0..15
    int e   = r2 & 7;            // 0..7
    int row = g * 16 + rr;       // 0..527
    int k   = kt * 32 + q * 8 + e;
    float v = 0.f;
    if (row < 512)      v = cw[row * 2048 + k];
    else if (row < 522) v = sw[(row - 512) * 2048 + k];
    else if (row < 525) v = camw[(row - 522) * 2048 + k];
    Wp[gid] = f2bf(v);
}

// ---- pack root/pose weights to bf16 [o2][K2]; cols 15360.. are the coord columns ----
__global__ void pack_w2_kernel(const float* __restrict__ root_w,
                               const float* __restrict__ pose_w,
                               unsigned short* __restrict__ W2p) {
    int gid = blockIdx.x * 256 + threadIdx.x;
    if (gid >= W2P_ELEMS) return;
    int o2 = gid / K2;
    int kk = gid - o2 * K2;
    float v = 0.f;
    if (o2 < 132) {
        const float* wr = (o2 < 6) ? (root_w + o2 * 15450) : (pose_w + (o2 - 6) * 15450);
        if (kk < 15360) {
            int j = kk >> 9;
            int o = kk & 511;
            v = wr[j * 515 + o];
        } else {
            int c = kk - 15360;
            if (c < 90) {
                int j = c / 3, d = c - 3 * j;
                v = wr[j * 515 + 512 + d];
            }
        }
    }
    W2p[gid] = f2bf(v);
}

// ---- fold BN(eval)+conv bias into per-channel scale/bias ----
__global__ void bn_prep_kernel(const float* cb, const float* g, const float* be,
                               const float* m, const float* v, float* sbws) {
    int o = blockIdx.x * 256 + threadIdx.x;
    if (o >= 512) return;
    float s = g[o] * rsqrtf(v[o] + 1e-5f);
    sbws[2 * o]     = s;
    sbws[2 * o + 1] = be[o] + s * (cb[o] - m[o]);
}

// ---- main fused kernel: per-batch conv GEMM (+pooled rows) + BN/ReLU + bilinear sample ----
// Pipelined: double-buffered LDS, A via global_load_lds (prefetch kt+1 during kt compute),
// one barrier per K-step.
__global__ __launch_bounds__(256, 2)
void conv_main_kernel(const float* __restrict__ img,
                      const float* __restrict__ jc,
                      const unsigned short* __restrict__ Wp,
                      const float* __restrict__ sbws,
                      const float* __restrict__ shape_b,
                      const float* __restrict__ cam_b,
                      unsigned short* __restrict__ sampled,
                      float* __restrict__ out) {
    __shared__ __align__(16) char smem[SMEM_SZ];
    const int t    = threadIdx.x;
    const int lane = t & 63;
    const int w    = t >> 6;
    const int l15  = lane & 15;
    const int quad = lane >> 4;
    const int b    = blockIdx.x;

    f32x4 acc[8][4];
    f32x4 accX;
    #pragma unroll
    for (int mi = 0; mi < 8; ++mi)
        #pragma unroll
        for (int nt = 0; nt < 4; ++nt)
            acc[mi][nt] = (f32x4){0.f, 0.f, 0.f, 0.f};
    accX = (f32x4){0.f, 0.f, 0.f, 0.f};

    // B: lane owns hw position = lane, channels w*8..w*8+7 per kt
    const float* gBbase = img + (size_t)b * 131072 + (size_t)(w * 8) * 64 + lane;
    float fb[8];

    auto loadB = [&](int kt) {
        const float* gB = gBbase + (size_t)(kt * 32) * 64;
        #pragma unroll
        for (int j = 0; j < 8; ++j) fb[j] = gB[j * 64];
    };
    auto writeB = [&](char* bbuf) {
        int4 bv;
        bv.x = (int)((uint32_t)f2bf(fb[0]) | ((uint32_t)f2bf(fb[1]) << 16));
        bv.y = (int)((uint32_t)f2bf(fb[2]) | ((uint32_t)f2bf(fb[3]) << 16));
        bv.z = (int)((uint32_t)f2bf(fb[4]) | ((uint32_t)f2bf(fb[5]) << 16));
        bv.w = (int)((uint32_t)f2bf(fb[6]) | ((uint32_t)f2bf(fb[7]) << 16));
        *(int4*)(bbuf + (lane >> 4) * 1024 + w * 256 + l15 * 16) = bv;
    };
    auto stageA = [&](int kt, char* abuf) {
        const unsigned short* src = Wp + (size_t)kt * 16896 + (size_t)(w * 8) * 512 + lane * 8;
        char* dst = abuf + w * 8192;
        #pragma unroll
        for (int i = 0; i < 8; ++i)
            gload16(src + i * 512, dst + i * 1024);
        if (w == 0)
            gload16(Wp + (size_t)kt * 16896 + 32 * 512 + lane * 8, abuf + 32768);
    };
    auto compute = [&](const char* abuf, const char* bbuf) {
        bf16x8 bfr0 = *(const bf16x8*)(bbuf + 0 * 1024 + quad * 256 + l15 * 16);
        bf16x8 bfr1 = *(const bf16x8*)(bbuf + 1 * 1024 + quad * 256 + l15 * 16);
        bf16x8 bfr2 = *(const bf16x8*)(bbuf + 2 * 1024 + quad * 256 + l15 * 16);
        bf16x8 bfr3 = *(const bf16x8*)(bbuf + 3 * 1024 + quad * 256 + l15 * 16);
        #pragma unroll
        for (int mi = 0; mi < 8; ++mi) {
            bf16x8 afr = *(const bf16x8*)(abuf + (w * 8 + mi) * 1024 + quad * 256 + l15 * 16);
            acc[mi][0] = __builtin_amdgcn_mfma_f32_16x16x32_bf16(afr, bfr0, acc[mi][0], 0, 0, 0);
            acc[mi][1] = __builtin_amdgcn_mfma_f32_16x16x32_bf16(afr, bfr1, acc[mi][1], 0, 0, 0);
            acc[mi][2] = __builtin_amdgcn_mfma_f32_16x16x32_bf16(afr, bfr2, acc[mi][2], 0, 0, 0);
            acc[mi][3] = __builtin_amdgcn_mfma_f32_16x16x32_bf16(afr, bfr3, acc[mi][3], 0, 0, 0);
        }
        {   // pooled rows 512..527 (shape_w/cam_w); wave w covers col-group w
            bf16x8 afrX = *(const bf16x8*)(abuf + 32768 + quad * 256 + l15 * 16);
            bf16x8 bfrW = *(const bf16x8*)(bbuf + w * 1024 + quad * 256 + l15 * 16);
            accX = __builtin_amdgcn_mfma_f32_16x16x32_bf16(afrX, bfrW, accX, 0, 0, 0);
        }
    };

    // prologue: stage kt=0 into buf0
    loadB(0);
    stageA(0, smem + ABUF0);
    writeB(smem + BBUF0);
    __syncthreads();            // drains vmcnt(0): A-lds complete

    #pragma unroll 2
    for (int kt = 0; kt < 64; ++kt) {
        char* acur = smem + ((kt & 1) ? ABUF1 : ABUF0);
        char* bcur = smem + ((kt & 1) ? BBUF1 : BBUF0);
        char* anxt = smem + ((kt & 1) ? ABUF0 : ABUF1);
        char* bnxt = smem + ((kt & 1) ? BBUF0 : BBUF1);
        if (kt < 63) {
            loadB(kt + 1);          // issue B global loads (regs)
            stageA(kt + 1, anxt);   // issue A global_load_lds (stays in flight)
        }
        compute(acur, bcur);        // ds_read + MFMA on current buffers
        if (kt < 63) writeB(bnxt);  // vmcnt-wait on fb, convert, ds_write
        __syncthreads();            // single drain+barrier per K-step
    }

    // staging LDS dead; reuse bytes [0,65536) as f (512 rows x 64 pos bf16, XOR swizzle)
    const float2* sb2 = (const float2*)sbws;
    #pragma unroll
    for (int mi = 0; mi < 8; ++mi) {
        #pragma unroll
        for (int r = 0; r < 4; ++r) {
            int row = w * 128 + mi * 16 + quad * 4 + r;
            float2 sb = sb2[row];
            #pragma unroll
            for (int nt = 0; nt < 4; ++nt) {
                int col = nt * 16 + l15;
                float v = fmaxf(acc[mi][nt][r] * sb.x + sb.y, 0.f);
                *(unsigned short*)(smem + row * 128 + (((col + row) & 63) << 1)) = f2bf(v);
            }
        }
    }
    // shape/cam: per-wave shuffle reduce (16 positions), cross-wave via LDS red area
    float* red = (float*)(smem + REDOFF);
    #pragma unroll
    for (int r = 0; r < 4; ++r) {
        float v = accX[r];
        v += __shfl_xor(v, 1);
        v += __shfl_xor(v, 2);
        v += __shfl_xor(v, 4);
        v += __shfl_xor(v, 8);
        if (l15 == 0) red[w * 16 + quad * 4 + r] = v;
    }
    __syncthreads();

    if (t < 16) {
        float v = (red[t] + red[16 + t] + red[32 + t] + red[48 + t]) * 0.015625f;
        if (t < 10)      out[67584 + b * 10 + t] = v + shape_b[t];
        else if (t < 13) out[72704 + b * 3 + (t - 10)] = v + cam_b[t - 10];
    }
    // append joint coords (bf16) as K-columns 15360..15455 of samp (pad 90..95 = 0)
    const float* jcb = jc + b * 90;
    if (t < 96) {
        float v = (t < 90) ? jcb[t] : 0.f;
        sampled[(size_t)b * K2 + 15360 + t] = f2bf(v);
    }

    // bilinear sampling: thread handles channels o=2t,2t+1; joint j == s for all threads
    unsigned int* outsamp = (unsigned int*)(sampled + (size_t)b * K2);
    const int o = 2 * t;
    for (int s = 0; s < 30; ++s) {
        float x = jcb[s * 3 + 0];
        float y = jcb[s * 3 + 1];
        float x0f = floorf(x), y0f = floorf(y);
        int x0 = (int)x0f, y0 = (int)y0f;
        int x1 = x0 + 1, y1 = y0 + 1;
        float wx1 = x - x0f, wy1 = y - y0f;
        float wx0 = 1.f - wx1, wy0 = 1.f - wy1;
        float vx0 = (x0 >= 0 && x0 < 8) ? 1.f : 0.f;
        float vx1 = (x1 >= 0 && x1 < 8) ? 1.f : 0.f;
        float vy0 = (y0 >= 0 && y0 < 8) ? 1.f : 0.f;
        float vy1 = (y1 >= 0 && y1 < 8) ? 1.f : 0.f;
        int cx0 = min(max(x0, 0), 7), cx1 = min(max(x1, 0), 7);
        int cy0 = min(max(y0, 0), 7), cy1 = min(max(y1, 0), 7);
        int p00 = cy0 * 8 + cx0, p01 = cy0 * 8 + cx1;
        int p10 = cy1 * 8 + cx0, p11 = cy1 * 8 + cx1;
        float w00 = wy0 * wx0 * vy0 * vx0, w01 = wy0 * wx1 * vy0 * vx1;
        float w10 = wy1 * wx0 * vy1 * vx0, w11 = wy1 * wx1 * vy1 * vx1;
        float vA = w00 * bf2f(*(unsigned short*)(smem + o * 128 + (((p00 + o) & 63) << 1)))
                 + w01 * bf2f(*(unsigned short*)(smem + o * 128 + (((p01 + o) & 63) << 1)))
                 + w10 * bf2f(*(unsigned short*)(smem + o * 128 + (((p10 + o) & 63) << 1)))
                 + w11 * bf2f(*(unsigned short*)(smem + o * 128 + (((p11 + o) & 63) << 1)));
        int o1 = o + 1;
        float vB = w00 * bf2f(*(unsigned short*)(smem + o1 * 128 + (((p00 + o1) & 63) << 1)))
                 + w01 * bf2f(*(unsigned short*)(smem + o1 * 128 + (((p01 + o1) & 63) << 1)))
                 + w10 * bf2f(*(unsigned short*)(smem + o1 * 128 + (((p10 + o1) & 63) << 1)))
                 + w11 * bf2f(*(unsigned short*)(smem + o1 * 128 + (((p11 + o1) & 63) << 1)));
        outsamp[s * 256 + t] = (uint32_t)f2bf(vA) | ((uint32_t)f2bf(vB) << 16);
    }
}

// ---- head GEMM: partials(31x8 blocks of 64x144) = feat(512xK2)bf16 @ W2p^T, K split by joint ----
__global__ __launch_bounds__(256, 4)
void gemm2_kernel(const unsigned short* __restrict__ sampled,
                  const unsigned short* __restrict__ W2p,
                  float* __restrict__ part) {
    __shared__ __align__(16) char smem[16640];   // A: 64*80=5120, B: 144*80=11520
    const int t    = threadIdx.x;
    const int lane = t & 63;
    const int w    = t >> 6;
    const int l15  = lane & 15;
    const int quad = lane >> 4;
    const int m0   = blockIdx.x * 64;
    const int j    = blockIdx.y;
    const int k0   = j * 512;              // j==30 -> 15360 (coord columns)
    const int ktn  = (j == 30) ? 3 : 16;

    f32x4 acc[9];
    #pragma unroll
    for (int nt = 0; nt < 9; ++nt) acc[nt] = (f32x4){0.f, 0.f, 0.f, 0.f};

    for (int kt = 0; kt < ktn; ++kt) {
        __syncthreads();
        {
            int r = t >> 2, ci = t & 3;
            int4 d = *(const int4*)(sampled + (size_t)(m0 + r) * K2 + k0 + kt * 32 + ci * 8);
            *(int4*)(smem + r * 80 + ci * 16) = d;
        }
        #pragma unroll
        for (int i = 0; i < 3; ++i) {
            int c2 = t + 256 * i;
            if (c2 < 576) {
                int r = c2 >> 2, ci = c2 & 3;
                int4 d = *(const int4*)(W2p + (size_t)r * K2 + k0 + kt * 32 + ci * 8);
                *(int4*)(smem + 5120 + r * 80 + ci * 16) = d;
            }
        }
        __syncthreads();
        bf16x8 a = *(const bf16x8*)(smem + (w * 16 + l15) * 80 + quad * 16);
        #pragma unroll
        for (int nt = 0; nt < 9; ++nt) {
            bf16x8 bfv = *(const bf16x8*)(smem + 5120 + (nt * 16 + l15) * 80 + quad * 16);
            acc[nt] = __builtin_amdgcn_mfma_f32_16x16x32_bf16(a, bfv, acc[nt], 0, 0, 0);
        }
    }
    float* pout = part + (size_t)(j * 8 + blockIdx.x) * 9216;   // 64*144
    #pragma unroll
    for (int nt = 0; nt < 9; ++nt) {
        #pragma unroll
        for (int r = 0; r < 4; ++r) {
            pout[(w * 16 + quad * 4 + r) * 144 + nt * 16 + l15] = acc[nt][r];
        }
    }
}

// ---- sum 31 K-partials + bias -> final root/pose outputs ----
__global__ void reduce_out_kernel(const float* __restrict__ part,
                                  const float* __restrict__ root_b,
                                  const float* __restrict__ pose_b,
                                  float* __restrict__ out) {
    int gid = blockIdx.x * 256 + threadIdx.x;    // exactly 67584
    int m  = gid / 132;
    int o2 = gid - m * 132;
    float s = (o2 < 6) ? root_b[o2] : pose_b[o2 - 6];
    const float* p = part + (size_t)(m >> 6) * 9216 + (m & 63) * 144 + o2;
    #pragma unroll
    for (int j = 0; j < 31; ++j) s += p[(size_t)j * 8 * 9216];
    if (o2 < 6) out[m * 6 + o2] = s;
    else        out[3072 + m * 126 + (o2 - 6)] = s;
}

extern "C" void kernel_launch(void* const* d_in, const int* in_sizes, int n_in,
                              void* d_out, int out_size, void* d_ws, size_t ws_size,
                              hipStream_t stream) {
    const float* img     = (const float*)d_in[0];
    const float* jc      = (const float*)d_in[1];
    const float* conv_w  = (const float*)d_in[2];
    const float* conv_b  = (const float*)d_in[3];
    const float* bn_g    = (const float*)d_in[4];
    const float* bn_be   = (const float*)d_in[5];
    const float* bn_m    = (const float*)d_in[6];
    const float* bn_v    = (const float*)d_in[7];
    const float* root_w  = (const float*)d_in[8];
    const float* root_b  = (const float*)d_in[9];
    const float* pose_w  = (const float*)d_in[10];
    const float* pose_b  = (const float*)d_in[11];
    const float* shape_w = (const float*)d_in[12];
    const float* shape_b = (const float*)d_in[13];
    const float* cam_w   = (const float*)d_in[14];
    const float* cam_b   = (const float*)d_in[15];
    float* out = (float*)d_out;
    char* ws = (char*)d_ws;

    unsigned short* Wp   = (unsigned short*)(ws);                    // 2,162,688 B
    unsigned short* W2p  = (unsigned short*)(ws + 2162688);          // 4,451,328 B
    unsigned short* samp = (unsigned short*)(ws + 6614016);          // 15,826,944 B
    float* part          = (float*)(ws + 22440960);                  // 9,142,272 B
    float* sbws          = (float*)(ws + 31583232);                  // 4,096 B

    pack_convw_kernel<<<4224, 256, 0, stream>>>(conv_w, shape_w, cam_w, Wp);
    pack_w2_kernel<<<8694, 256, 0, stream>>>(root_w, pose_w, W2p);
    bn_prep_kernel<<<2, 256, 0, stream>>>(conv_b, bn_g, bn_be, bn_m, bn_v, sbws);
    conv_main_kernel<<<512, 256, 0, stream>>>(img, jc, Wp, sbws, shape_b, cam_b,
                                              samp, out);
    gemm2_kernel<<<dim3(8, 31), 256, 0, stream>>>(samp, W2p, part);
    reduce_out_kernel<<<264, 256, 0, stream>>>(part, root_b, pose_b, out);
}

// Round 6
// 464.176 us; speedup vs baseline: 1.0174x; 1.0152x over previous
//
#include <hip/hip_runtime.h>
#include <stdint.h>

typedef __attribute__((ext_vector_type(8))) short bf16x8;
typedef __attribute__((ext_vector_type(4))) float f32x4;

__device__ __forceinline__ unsigned short f2bf(float f) {
    union { float f; uint32_t u; } v; v.f = f;
    uint32_t r = (v.u + 0x7FFFu + ((v.u >> 16) & 1u)) >> 16;
    return (unsigned short)r;
}
__device__ __forceinline__ float bf2f(unsigned short u) {
    union { uint32_t u; float f; } v; v.u = ((uint32_t)u) << 16; return v.f;
}

// async global->LDS, 16B per lane; LDS dest = wave-uniform base + lane*16
__device__ __forceinline__ void gload16(const void* g, void* l) {
    __builtin_amdgcn_global_load_lds(
        (const __attribute__((address_space(1))) unsigned int*)g,
        (__attribute__((address_space(3))) unsigned int*)l, 16, 0, 0);
}

#define WP_ELEMS  1081344      // 64 ktiles * 33 groups * 512 bf16
#define K2        15456        // head-GEMM K: 30*512 sampled + 96 coord slots (90 used)
#define W2P_ELEMS (144 * K2)   // 2,225,664

// conv_main LDS layout (bytes)
#define ABUF0  0
#define ABUF1  33792
#define BBUF0  67584
#define BBUF1  71680
#define REDOFF 75776
#define SMEM_SZ 76032

// counted waits: keep the 8 newest VMEM ops (B loads for kt+2) in flight across barrier
#define WAIT_VM8 asm volatile("s_waitcnt vmcnt(8) lgkmcnt(0)" ::: "memory")
#define WAIT_VM0 asm volatile("s_waitcnt vmcnt(0) lgkmcnt(0)" ::: "memory")
#define BAR do { __builtin_amdgcn_s_barrier(); __builtin_amdgcn_sched_barrier(0); } while (0)

// ---- fused prep: pack conv weights + pack head weights + BN fold (one launch) ----
// Wp layout: [kt][group g=row>>4][kchunk q][row&15][e] -> chunk-major 1024B groups,
// exactly the LDS image for global_load_lds + conflict-free ds_read_b128.
__global__ void prep_kernel(const float* __restrict__ cw,
                            const float* __restrict__ sw,
                            const float* __restrict__ camw,
                            const float* __restrict__ root_w,
                            const float* __restrict__ pose_w,
                            const float* __restrict__ cb, const float* __restrict__ g,
                            const float* __restrict__ be, const float* __restrict__ m,
                            const float* __restrict__ vv,
                            unsigned short* __restrict__ Wp,
                            unsigned short* __restrict__ W2p,
                            float* __restrict__ sbws) {
    int gid = blockIdx.x * 256 + threadIdx.x;
    if (gid < WP_ELEMS) {
        int kt  = gid / 16896;
        int rem = gid - kt * 16896;
        int gg  = rem >> 9;          // 0..32
        int r2  = rem & 511;
        int q   = r2 >> 7;           // 0..3
        int rr  = (r2 >> 3) & 15;    // 0..15
        int e   = r2 & 7;            // 0..7
        int row = gg * 16 + rr;      // 0..527
        int k   = kt * 32 + q * 8 + e;
        float v = 0.f;
        if (row < 512)      v = cw[row * 2048 + k];
        else if (row < 522) v = sw[(row - 512) * 2048 + k];
        else if (row < 525) v = camw[(row - 522) * 2048 + k];
        Wp[gid] = f2bf(v);
        return;
    }
    gid -= WP_ELEMS;
    if (gid < W2P_ELEMS) {
        int o2 = gid / K2;
        int kk = gid - o2 * K2;
        float v = 0.f;
        if (o2 < 132) {
            const float* wr = (o2 < 6) ? (root_w + o2 * 15450) : (pose_w + (o2 - 6) * 15450);
            if (kk < 15360) {
                int j = kk >> 9;
                int o = kk & 511;
                v = wr[j * 515 + o];
            } else {
                int c = kk - 15360;
                if (c < 90) {
                    int j = c / 3, d = c - 3 * j;
                    v = wr[j * 515 + 512 + d];
                }
            }
        }
        W2p[gid] = f2bf(v);
        return;
    }
    gid -= W2P_ELEMS;
    if (gid < 512) {
        float s = g[gid] * rsqrtf(vv[gid] + 1e-5f);
        sbws[2 * gid]     = s;
        sbws[2 * gid + 1] = be[gid] + s * (cb[gid] - m[gid]);
    }
}

// ---- main fused kernel: per-batch conv GEMM (+pooled rows) + BN/ReLU + bilinear sample ----
// Counted-vmcnt pipeline: uniform 17 VMEM/iter per wave (9 A-lds + 8 B-dword),
// B regs double-buffered (2 iterations deep), raw s_barrier with vmcnt(8).
__global__ __launch_bounds__(256, 2)
void conv_main_kernel(const float* __restrict__ img,
                      const float* __restrict__ jc,
                      const unsigned short* __restrict__ Wp,
                      const float* __restrict__ sbws,
                      const float* __restrict__ shape_b,
                      const float* __restrict__ cam_b,
                      unsigned short* __restrict__ sampled,
                      float* __restrict__ out) {
    __shared__ __align__(16) char smem[SMEM_SZ];
    const int t    = threadIdx.x;
    const int lane = t & 63;
    const int w    = t >> 6;
    const int l15  = lane & 15;
    const int quad = lane >> 4;
    const int b    = blockIdx.x;

    f32x4 acc[8][4];
    f32x4 accX;
    #pragma unroll
    for (int mi = 0; mi < 8; ++mi)
        #pragma unroll
        for (int nt = 0; nt < 4; ++nt)
            acc[mi][nt] = (f32x4){0.f, 0.f, 0.f, 0.f};
    accX = (f32x4){0.f, 0.f, 0.f, 0.f};

    // B: lane owns hw position = lane, channels w*8..w*8+7 per kt
    const float* gBbase = img + (size_t)b * 131072 + (size_t)(w * 8) * 64 + lane;
    float fbA[8], fbB[8];

    auto loadB = [&](int kt, float* fb) {
        const float* gB = gBbase + (size_t)(kt * 32) * 64;
        #pragma unroll
        for (int j = 0; j < 8; ++j) fb[j] = gB[j * 64];
    };
    auto writeB = [&](const float* fb, char* bbuf) {
        int4 bv;
        bv.x = (int)((uint32_t)f2bf(fb[0]) | ((uint32_t)f2bf(fb[1]) << 16));
        bv.y = (int)((uint32_t)f2bf(fb[2]) | ((uint32_t)f2bf(fb[3]) << 16));
        bv.z = (int)((uint32_t)f2bf(fb[4]) | ((uint32_t)f2bf(fb[5]) << 16));
        bv.w = (int)((uint32_t)f2bf(fb[6]) | ((uint32_t)f2bf(fb[7]) << 16));
        *(int4*)(bbuf + (lane >> 4) * 1024 + w * 256 + l15 * 16) = bv;
    };
    // uniform 9 global_load_lds per wave (all waves redundantly stage the X group)
    auto stageA = [&](int kt, char* abuf) {
        const unsigned short* base = Wp + (size_t)kt * 16896;
        const unsigned short* src  = base + (size_t)(w * 8) * 512 + lane * 8;
        char* dst = abuf + w * 8192;
        #pragma unroll
        for (int i = 0; i < 8; ++i)
            gload16(src + i * 512, dst + i * 1024);
        gload16(base + 32 * 512 + lane * 8, abuf + 32768);
    };
    auto compute = [&](const char* abuf, const char* bbuf) {
        bf16x8 bfr0 = *(const bf16x8*)(bbuf + 0 * 1024 + quad * 256 + l15 * 16);
        bf16x8 bfr1 = *(const bf16x8*)(bbuf + 1 * 1024 + quad * 256 + l15 * 16);
        bf16x8 bfr2 = *(const bf16x8*)(bbuf + 2 * 1024 + quad * 256 + l15 * 16);
        bf16x8 bfr3 = *(const bf16x8*)(bbuf + 3 * 1024 + quad * 256 + l15 * 16);
        #pragma unroll
        for (int mi = 0; mi < 8; ++mi) {
            bf16x8 afr = *(const bf16x8*)(abuf + (w * 8 + mi) * 1024 + quad * 256 + l15 * 16);
            acc[mi][0] = __builtin_amdgcn_mfma_f32_16x16x32_bf16(afr, bfr0, acc[mi][0], 0, 0, 0);
            acc[mi][1] = __builtin_amdgcn_mfma_f32_16x16x32_bf16(afr, bfr1, acc[mi][1], 0, 0, 0);
            acc[mi][2] = __builtin_amdgcn_mfma_f32_16x16x32_bf16(afr, bfr2, acc[mi][2], 0, 0, 0);
            acc[mi][3] = __builtin_amdgcn_mfma_f32_16x16x32_bf16(afr, bfr3, acc[mi][3], 0, 0, 0);
        }
        {   // pooled rows 512..527 (shape_w/cam_w); wave w covers col-group w
            bf16x8 afrX = *(const bf16x8*)(abuf + 32768 + quad * 256 + l15 * 16);
            bf16x8 bfrW = *(const bf16x8*)(bbuf + w * 1024 + quad * 256 + l15 * 16);
            accX = __builtin_amdgcn_mfma_f32_16x16x32_bf16(afrX, bfrW, accX, 0, 0, 0);
        }
    };

    // prologue: B(0)->fbA, stage A(0), B(1)->fbB, write B(0); keep L1 in flight
    loadB(0, fbA);
    stageA(0, smem + ABUF0);
    loadB(1, fbB);
    writeB(fbA, smem + BBUF0);   // compiler waits only for fbA (newer ops stay in flight)
    WAIT_VM8;                    // drain S(0) A-lds (L(1)'s 8 ops remain in flight)
    BAR;

    // steady state per iteration kt:
    //   in-flight on entry: L(kt+1) B-regs (<=8 ops)
    //   issue S(kt+1) A-lds (9), L(kt+2) B-regs (8); compute kt; write B(kt+1);
    //   wait vmcnt(8) -> S(kt+1) drained, L(kt+2) stays in flight; barrier.
    #pragma unroll 1
    for (int kt = 0; kt < 64; kt += 2) {
        {   // even kt: cur = buf0, nxt = buf1; fbB holds B(kt+1), fbA is load target
            if (kt < 63) stageA(kt + 1, smem + ABUF1);
            if (kt < 62) loadB(kt + 2, fbA);
            compute(smem + ABUF0, smem + BBUF0);
            if (kt < 63) writeB(fbB, smem + BBUF1);
            if (kt < 62) { WAIT_VM8; } else { WAIT_VM0; }
            BAR;
        }
        {   // odd kt+1: cur = buf1, nxt = buf0; fbA holds B(kt+2), fbB is load target
            int k1 = kt + 1;
            if (k1 < 63) stageA(k1 + 1, smem + ABUF0);
            if (k1 < 62) loadB(k1 + 2, fbB);
            compute(smem + ABUF1, smem + BBUF1);
            if (k1 < 63) writeB(fbA, smem + BBUF0);
            if (k1 < 62) { WAIT_VM8; } else { WAIT_VM0; }
            BAR;
        }
    }

    __syncthreads();   // staging LDS dead; reuse bytes [0,65536) as f (512 rows x 64 pos bf16, XOR swizzle)
    const float2* sb2 = (const float2*)sbws;
    #pragma unroll
    for (int mi = 0; mi < 8; ++mi) {
        #pragma unroll
        for (int r = 0; r < 4; ++r) {
            int row = w * 128 + mi * 16 + quad * 4 + r;
            float2 sb = sb2[row];
            #pragma unroll
            for (int nt = 0; nt < 4; ++nt) {
                int col = nt * 16 + l15;
                float v = fmaxf(acc[mi][nt][r] * sb.x + sb.y, 0.f);
                *(unsigned short*)(smem + row * 128 + (((col + row) & 63) << 1)) = f2bf(v);
            }
        }
    }
    // shape/cam: per-wave shuffle reduce (16 positions), cross-wave via LDS red area
    float* red = (float*)(smem + REDOFF);
    #pragma unroll
    for (int r = 0; r < 4; ++r) {
        float v = accX[r];
        v += __shfl_xor(v, 1);
        v += __shfl_xor(v, 2);
        v += __shfl_xor(v, 4);
        v += __shfl_xor(v, 8);
        if (l15 == 0) red[w * 16 + quad * 4 + r] = v;
    }
    __syncthreads();

    if (t < 16) {
        float v = (red[t] + red[16 + t] + red[32 + t] + red[48 + t]) * 0.015625f;
        if (t < 10)      out[67584 + b * 10 + t] = v + shape_b[t];
        else if (t < 13) out[72704 + b * 3 + (t - 10)] = v + cam_b[t - 10];
    }
    // append joint coords (bf16) as K-columns 15360..15455 of samp (pad 90..95 = 0)
    const float* jcb = jc + b * 90;
    if (t < 96) {
        float v = (t < 90) ? jcb[t] : 0.f;
        sampled[(size_t)b * K2 + 15360 + t] = f2bf(v);
    }

    // bilinear sampling: thread handles channels o=2t,2t+1; joint j == s for all threads
    unsigned int* outsamp = (unsigned int*)(sampled + (size_t)b * K2);
    const int o = 2 * t;
    for (int s = 0; s < 30; ++s) {
        float x = jcb[s * 3 + 0];
        float y = jcb[s * 3 + 1];
        float x0f = floorf(x), y0f = floorf(y);
        int x0 = (int)x0f, y0 = (int)y0f;
        int x1 = x0 + 1, y1 = y0 + 1;
        float wx1 = x - x0f, wy1 = y - y0f;
        float wx0 = 1.f - wx1, wy0 = 1.f - wy1;
        float vx0 = (x0 >= 0 && x0 < 8) ? 1.f : 0.f;
        float vx1 = (x1 >= 0 && x1 < 8) ? 1.f : 0.f;
        float vy0 = (y0 >= 0 && y0 < 8) ? 1.f : 0.f;
        float vy1 = (y1 >= 0 && y1 < 8) ? 1.f : 0.f;
        int cx0 = min(max(x0, 0), 7), cx1 = min(max(x1, 0), 7);
        int cy0 = min(max(y0, 0), 7), cy1 = min(max(y1, 0), 7);
        int p00 = cy0 * 8 + cx0, p01 = cy0 * 8 + cx1;
        int p10 = cy1 * 8 + cx0, p11 = cy1 * 8 + cx1;
        float w00 = wy0 * wx0 * vy0 * vx0, w01 = wy0 * wx1 * vy0 * vx1;
        float w10 = wy1 * wx0 * vy1 * vx0, w11 = wy1 * wx1 * vy1 * vx1;
        float vA = w00 * bf2f(*(unsigned short*)(smem + o * 128 + (((p00 + o) & 63) << 1)))
                 + w01 * bf2f(*(unsigned short*)(smem + o * 128 + (((p01 + o) & 63) << 1)))
                 + w10 * bf2f(*(unsigned short*)(smem + o * 128 + (((p10 + o) & 63) << 1)))
                 + w11 * bf2f(*(unsigned short*)(smem + o * 128 + (((p11 + o) & 63) << 1)));
        int o1 = o + 1;
        float vB = w00 * bf2f(*(unsigned short*)(smem + o1 * 128 + (((p00 + o1) & 63) << 1)))
                 + w01 * bf2f(*(unsigned short*)(smem + o1 * 128 + (((p01 + o1) & 63) << 1)))
                 + w10 * bf2f(*(unsigned short*)(smem + o1 * 128 + (((p10 + o1) & 63) << 1)))
                 + w11 * bf2f(*(unsigned short*)(smem + o1 * 128 + (((p11 + o1) & 63) << 1)));
        outsamp[s * 256 + t] = (uint32_t)f2bf(vA) | ((uint32_t)f2bf(vB) << 16);
    }
}

// ---- head GEMM: partials(31x8 blocks of 64x144) = feat(512xK2)bf16 @ W2p^T, K split by joint ----
__global__ __launch_bounds__(256, 4)
void gemm2_kernel(const unsigned short* __restrict__ sampled,
                  const unsigned short* __restrict__ W2p,
                  float* __restrict__ part) {
    __shared__ __align__(16) char smem[16640];   // A: 64*80=5120, B: 144*80=11520
    const int t    = threadIdx.x;
    const int lane = t & 63;
    const int w    = t >> 6;
    const int l15  = lane & 15;
    const int quad = lane >> 4;
    const int m0   = blockIdx.x * 64;
    const int j    = blockIdx.y;
    const int k0   = j * 512;              // j==30 -> 15360 (coord columns)
    const int ktn  = (j == 30) ? 3 : 16;

    f32x4 acc[9];
    #pragma unroll
    for (int nt = 0; nt < 9; ++nt) acc[nt] = (f32x4){0.f, 0.f, 0.f, 0.f};

    for (int kt = 0; kt < ktn; ++kt) {
        __syncthreads();
        {
            int r = t >> 2, ci = t & 3;
            int4 d = *(const int4*)(sampled + (size_t)(m0 + r) * K2 + k0 + kt * 32 + ci * 8);
            *(int4*)(smem + r * 80 + ci * 16) = d;
        }
        #pragma unroll
        for (int i = 0; i < 3; ++i) {
            int c2 = t + 256 * i;
            if (c2 < 576) {
                int r = c2 >> 2, ci = c2 & 3;
                int4 d = *(const int4*)(W2p + (size_t)r * K2 + k0 + kt * 32 + ci * 8);
                *(int4*)(smem + 5120 + r * 80 + ci * 16) = d;
            }
        }
        __syncthreads();
        bf16x8 a = *(const bf16x8*)(smem + (w * 16 + l15) * 80 + quad * 16);
        #pragma unroll
        for (int nt = 0; nt < 9; ++nt) {
            bf16x8 bfv = *(const bf16x8*)(smem + 5120 + (nt * 16 + l15) * 80 + quad * 16);
            acc[nt] = __builtin_amdgcn_mfma_f32_16x16x32_bf16(a, bfv, acc[nt], 0, 0, 0);
        }
    }
    float* pout = part + (size_t)(j * 8 + blockIdx.x) * 9216;   // 64*144
    #pragma unroll
    for (int nt = 0; nt < 9; ++nt) {
        #pragma unroll
        for (int r = 0; r < 4; ++r) {
            pout[(w * 16 + quad * 4 + r) * 144 + nt * 16 + l15] = acc[nt][r];
        }
    }
}

// ---- sum 31 K-partials + bias -> final root/pose outputs ----
__global__ void reduce_out_kernel(const float* __restrict__ part,
                                  const float* __restrict__ root_b,
                                  const float* __restrict__ pose_b,
                                  float* __restrict__ out) {
    int gid = blockIdx.x * 256 + threadIdx.x;    // exactly 67584
    int m  = gid / 132;
    int o2 = gid - m * 132;
    float s = (o2 < 6) ? root_b[o2] : pose_b[o2 - 6];
    const float* p = part + (size_t)(m >> 6) * 9216 + (m & 63) * 144 + o2;
    #pragma unroll
    for (int j = 0; j < 31; ++j) s += p[(size_t)j * 8 * 9216];
    if (o2 < 6) out[m * 6 + o2] = s;
    else        out[3072 + m * 126 + (o2 - 6)] = s;
}

extern "C" void kernel_launch(void* const* d_in, const int* in_sizes, int n_in,
                              void* d_out, int out_size, void* d_ws, size_t ws_size,
                              hipStream_t stream) {
    const float* img     = (const float*)d_in[0];
    const float* jc      = (const float*)d_in[1];
    const float* conv_w  = (const float*)d_in[2];
    const float* conv_b  = (const float*)d_in[3];
    const float* bn_g    = (const float*)d_in[4];
    const float* bn_be   = (const float*)d_in[5];
    const float* bn_m    = (const float*)d_in[6];
    const float* bn_v    = (const float*)d_in[7];
    const float* root_w  = (const float*)d_in[8];
    const float* root_b  = (const float*)d_in[9];
    const float* pose_w  = (const float*)d_in[10];
    const float* pose_b  = (const float*)d_in[11];
    const float* shape_w = (const float*)d_in[12];
    const float* shape_b = (const float*)d_in[13];
    const float* cam_w   = (const float*)d_in[14];
    const float* cam_b   = (const float*)d_in[15];
    float* out = (float*)d_out;
    char* ws = (char*)d_ws;

    unsigned short* Wp   = (unsigned short*)(ws);                    // 2,162,688 B
    unsigned short* W2p  = (unsigned short*)(ws + 2162688);          // 4,451,328 B
    unsigned short* samp = (unsigned short*)(ws + 6614016);          // 15,826,944 B
    float* part          = (float*)(ws + 22440960);                  // 9,142,272 B
    float* sbws          = (float*)(ws + 31583232);                  // 4,096 B

    // 12920 blocks cover WP_ELEMS + W2P_ELEMS + 512 exactly
    prep_kernel<<<12920, 256, 0, stream>>>(conv_w, shape_w, cam_w, root_w, pose_w,
                                           conv_b, bn_g, bn_be, bn_m, bn_v,
                                           Wp, W2p, sbws);
    conv_main_kernel<<<512, 256, 0, stream>>>(img, jc, Wp, sbws, shape_b, cam_b,
                                              samp, out);
    gemm2_kernel<<<dim3(8, 31), 256, 0, stream>>>(samp, W2p, part);
    reduce_out_kernel<<<264, 256, 0, stream>>>(part, root_b, pose_b, out);
}